// Round 3
// baseline (357.152 us; speedup 1.0000x reference)
//
#include <hip/hip_runtime.h>
#include <hip/hip_bf16.h>
#include <stdint.h>

#define N_PTS 131072
#define NC 256
#define NSEG 16
#define BN_EPSF 1e-5f
#define BJ 264  // padded LDS row stride (shorts) for B tile: 2-way-free bank aliasing

typedef __attribute__((ext_vector_type(8))) short bf16x8;
typedef __attribute__((ext_vector_type(4))) float f32x4;

__device__ __forceinline__ unsigned short f2bf(float f) {
  union { float f; uint32_t u; } v; v.f = f;
  uint32_t u = v.u;
  uint32_t r = (u + 0x7fffu + ((u >> 16) & 1u)) >> 16;
  return (unsigned short)r;
}
__device__ __forceinline__ float bf2f(unsigned short h) {
  union { uint32_t u; float f; } v; v.u = ((uint32_t)h) << 16; return v.f;
}

// ------- prep: zero stats region (4608 floats) + transpose W1_top -> bf16 [n][k] -------
// 16 blocks. Stats zeroing and transpose are independent; stream order guarantees
// completion before k_segsum / k_gemm consume them.
__global__ __launch_bounds__(256) void k_prep(const float* __restrict__ W1,
                                              unsigned short* __restrict__ w1t,
                                              float* __restrict__ stats) {
  __shared__ float tile[64][65];
  int t = threadIdx.x;
  int b = blockIdx.x;
  stats[b * 288 + t] = 0.f;
  if (t < 32) stats[b * 288 + 256 + t] = 0.f;
  int bx = b & 3, by = b >> 2;
  int k0 = by * 64, j0 = bx * 64;
  int r = t >> 6, c = t & 63;
#pragma unroll
  for (int i = 0; i < 16; ++i) {
    int kk = r + i * 4;
    tile[kk][c] = W1[(size_t)(k0 + kk) * NC + j0 + c];
  }
  __syncthreads();
#pragma unroll
  for (int i = 0; i < 16; ++i) {
    int jj = r + i * 4;
    w1t[(size_t)(j0 + jj) * NC + k0 + c] = f2bf(tile[c][jj]);
  }
}

// ------- pass 1: x fp32 -> x_bf16, per-segment column sums -------
// 1024 blocks x 128 rows; branchless (<=2 segments per block, min seg ~7900 rows);
// 32 independent float4 loads per thread, fully unrolled.
__global__ __launch_bounds__(256) void k_segsum_convert(
    const float* __restrict__ x, const int* __restrict__ o,
    unsigned short* __restrict__ x_bf, float* __restrict__ seg_sums) {
  __shared__ int o_s[NSEG];
  __shared__ float s_acc[2][NC];
  int t = threadIdx.x;
  if (t < NSEG) o_s[t] = o[t];
  s_acc[0][t] = 0.f;
  s_acc[1][t] = 0.f;
  __syncthreads();
  int g = t >> 6, l = t & 63;
  int row0 = blockIdx.x * 128;
  int c0 = l * 4;
  int s0 = 0;
  while (o_s[s0] <= row0) ++s0;
  int e0 = o_s[s0];
  int s1 = (s0 < NSEG - 1) ? s0 + 1 : s0;  // if block fully inside seg, accB==0: harmless
  float4 accA = {0.f, 0.f, 0.f, 0.f}, accB = {0.f, 0.f, 0.f, 0.f};
  const float4* xv = (const float4*)x;
#pragma unroll
  for (int i = 0; i < 32; ++i) {
    int r = row0 + g + i * 4;
    float4 v = xv[(size_t)r * 64 + l];
    ushort4 b;
    b.x = f2bf(v.x); b.y = f2bf(v.y); b.z = f2bf(v.z); b.w = f2bf(v.w);
    *(ushort4*)(x_bf + (size_t)r * NC + c0) = b;
    bool inA = (r < e0);
    accA.x += inA ? v.x : 0.f; accB.x += inA ? 0.f : v.x;
    accA.y += inA ? v.y : 0.f; accB.y += inA ? 0.f : v.y;
    accA.z += inA ? v.z : 0.f; accB.z += inA ? 0.f : v.z;
    accA.w += inA ? v.w : 0.f; accB.w += inA ? 0.f : v.w;
  }
  atomicAdd(&s_acc[0][c0 + 0], accA.x);
  atomicAdd(&s_acc[0][c0 + 1], accA.y);
  atomicAdd(&s_acc[0][c0 + 2], accA.z);
  atomicAdd(&s_acc[0][c0 + 3], accA.w);
  atomicAdd(&s_acc[1][c0 + 0], accB.x);
  atomicAdd(&s_acc[1][c0 + 1], accB.y);
  atomicAdd(&s_acc[1][c0 + 2], accB.z);
  atomicAdd(&s_acc[1][c0 + 3], accB.w);
  __syncthreads();
  atomicAdd(&seg_sums[s0 * NC + t], s_acc[0][t]);
  atomicAdd(&seg_sums[s1 * NC + t], s_acc[1][t]);
}

// ------- tiny per-segment MLP: means -> y=relu(means@W2+b2) -> z=y@W1_bot+b1 -------
__global__ __launch_bounds__(256) void k_seg_mlp(
    const int* __restrict__ o, const float* __restrict__ seg_sums,
    const float* __restrict__ W1, const float* __restrict__ b1,
    const float* __restrict__ W2, const float* __restrict__ b2,
    float* __restrict__ z) {
  __shared__ float mean_s[NC];
  __shared__ float y_s[NC];
  int b = blockIdx.x, j = threadIdx.x;
  int start = (b == 0) ? 0 : o[b - 1];
  float inv = 1.f / (float)(o[b] - start);
  mean_s[j] = seg_sums[b * NC + j] * inv;
  __syncthreads();
  float a = b2[j];
  for (int k = 0; k < NC; ++k) a += mean_s[k] * W2[k * NC + j];
  y_s[j] = fmaxf(a, 0.f);
  __syncthreads();
  float a2 = b1[j];
  for (int k = 0; k < NC; ++k) a2 += y_s[k] * W1[(NC + k) * NC + j];
  z[b * NC + j] = a2;
}

// ------- main GEMM: h = x_bf @ W1_top + z[seg]; emit h_bf + BN col stats -------
// 2048 blocks; 128x128 tile; B col-tile (128x256 bf16, padded) resident in LDS,
// loaded once; A fragments direct from global; single barrier; fused epilogue.
__global__ __launch_bounds__(256) void k_gemm(
    const unsigned short* __restrict__ x_bf, const unsigned short* __restrict__ w1t,
    const int* __restrict__ o, const float* __restrict__ z,
    unsigned short* __restrict__ h_bf,
    float* __restrict__ colsum, float* __restrict__ colsumsq) {
  __shared__ __align__(16) unsigned short lB[128 * BJ];
  __shared__ float s_sum[128];
  __shared__ float s_sq[128];
  __shared__ int o_s[NSEG];

  int t = threadIdx.x;
  int lane = t & 63, w = t >> 6;
  int wr = w >> 1, wc = w & 1;
  int bid = blockIdx.x;
  // pair blocks sharing an A row-tile 8 apart -> same XCD slot, adjacent in time
  int rt = (bid & 7) | ((bid >> 4) << 3);
  int ct = (bid >> 3) & 1;
  const int row0 = rt * 128, colT = ct * 128;

  if (t < 128) { s_sum[t] = 0.f; s_sq[t] = 0.f; }
  if (t < NSEG) o_s[t] = o[t];

  // stage full B tile: 128 cols x 256 k, padded stride BJ
  {
    const uint4* gsrc = (const uint4*)(w1t + (size_t)colT * NC);
#pragma unroll
    for (int i = 0; i < 16; ++i) {
      int c = t + i * 256;          // chunk of 8 bf16
      int j = c >> 5, kc = c & 31;
      uint4 v = gsrc[j * 32 + kc];  // w1t[(colT+j)*256 + kc*8]
      *(uint4*)(lB + j * BJ + kc * 8) = v;
    }
  }
  __syncthreads();

  f32x4 acc[4][4] = {};
  const unsigned short* aBase =
      x_bf + (size_t)(row0 + wr * 64 + (lane & 15)) * NC + (lane >> 4) * 8;
  const unsigned short* bBase = lB + (wc * 64 + (lane & 15)) * BJ + (lane >> 4) * 8;
#pragma unroll
  for (int kt = 0; kt < 8; ++kt) {
    bf16x8 af[4], bfr[4];
#pragma unroll
    for (int m = 0; m < 4; ++m)
      af[m] = *(const bf16x8*)(aBase + (size_t)m * 16 * NC + kt * 32);
#pragma unroll
    for (int n = 0; n < 4; ++n)
      bfr[n] = *(const bf16x8*)(bBase + n * 16 * BJ + kt * 32);
#pragma unroll
    for (int m = 0; m < 4; ++m)
#pragma unroll
      for (int n = 0; n < 4; ++n)
        acc[m][n] = __builtin_amdgcn_mfma_f32_16x16x32_bf16(af[m], bfr[n], acc[m][n], 0, 0, 0);
  }

  // epilogue: + z[seg], store h_bf, per-column sum/sumsq
  int s0 = 0;
  while (o_s[s0] <= row0) ++s0;
  int e0 = o_s[s0];
  int s1 = (s0 < NSEG - 1) ? s0 + 1 : s0;
  int cl = lane & 15, q = lane >> 4;
#pragma unroll
  for (int n = 0; n < 4; ++n) {
    int col = colT + wc * 64 + n * 16 + cl;
    float zA = z[s0 * NC + col], zB = z[s1 * NC + col];
    float ps = 0.f, pq = 0.f;
#pragma unroll
    for (int m = 0; m < 4; ++m) {
      int rbase = row0 + wr * 64 + m * 16 + q * 4;
#pragma unroll
      for (int r = 0; r < 4; ++r) {
        int row = rbase + r;
        float hv = acc[m][n][r] + ((row < e0) ? zA : zB);
        h_bf[(size_t)row * NC + col] = f2bf(hv);
        ps += hv; pq += hv * hv;
      }
    }
    ps += __shfl_xor(ps, 16, 64); ps += __shfl_xor(ps, 32, 64);
    pq += __shfl_xor(pq, 16, 64); pq += __shfl_xor(pq, 32, 64);
    if (q == 0) {
      atomicAdd(&s_sum[wc * 64 + n * 16 + cl], ps);
      atomicAdd(&s_sq[wc * 64 + n * 16 + cl], pq);
    }
  }
  __syncthreads();
  if (t < 128) {
    atomicAdd(&colsum[colT + t], s_sum[t]);
    atomicAdd(&colsumsq[colT + t], s_sq[t]);
  }
}

// ------- BN finalize + apply + ReLU, fused. 4 elems/thread. -------
// Each thread's 4 columns are fixed by t&63 -> compute scale/shift in registers
// from colsum/colsumsq/gamma/beta (L1-resident float4 loads); no LDS, no barrier.
__global__ __launch_bounds__(256) void k_bn_apply(
    const unsigned short* __restrict__ h_bf,
    const float* __restrict__ colsum, const float* __restrict__ colsumsq,
    const float* __restrict__ gamma, const float* __restrict__ beta,
    float* __restrict__ out) {
  int t = threadIdx.x;
  int c4 = t & 63;
  float4 cs = ((const float4*)colsum)[c4];
  float4 cq = ((const float4*)colsumsq)[c4];
  float4 gm = ((const float4*)gamma)[c4];
  float4 bt = ((const float4*)beta)[c4];
  const float invN = 1.f / (float)N_PTS;
  float4 sc, sh;
  {
    float mu, var;
    mu = cs.x * invN; var = cq.x * invN - mu * mu;
    sc.x = gm.x * rsqrtf(var + BN_EPSF); sh.x = bt.x - mu * sc.x;
    mu = cs.y * invN; var = cq.y * invN - mu * mu;
    sc.y = gm.y * rsqrtf(var + BN_EPSF); sh.y = bt.y - mu * sc.y;
    mu = cs.z * invN; var = cq.z * invN - mu * mu;
    sc.z = gm.z * rsqrtf(var + BN_EPSF); sh.z = bt.z - mu * sc.z;
    mu = cs.w * invN; var = cq.w * invN - mu * mu;
    sc.w = gm.w * rsqrtf(var + BN_EPSF); sh.w = bt.w - mu * sc.w;
  }
  size_t idx = (size_t)blockIdx.x * 256 + t;
  size_t l0 = idx * 4;
  uint2 hv = *(const uint2*)(h_bf + l0);
  float f0 = bf2f((unsigned short)(hv.x & 0xffffu));
  float f1 = bf2f((unsigned short)(hv.x >> 16));
  float f2 = bf2f((unsigned short)(hv.y & 0xffffu));
  float f3 = bf2f((unsigned short)(hv.y >> 16));
  float4 o0;
  o0.x = fmaxf(f0 * sc.x + sh.x, 0.f);
  o0.y = fmaxf(f1 * sc.y + sh.y, 0.f);
  o0.z = fmaxf(f2 * sc.z + sh.z, 0.f);
  o0.w = fmaxf(f3 * sc.w + sh.w, 0.f);
  *(float4*)(out + l0) = o0;
}

extern "C" void kernel_launch(void* const* d_in, const int* in_sizes, int n_in,
                              void* d_out, int out_size, void* d_ws, size_t ws_size,
                              hipStream_t stream) {
  const float* x = (const float*)d_in[0];
  const int* o = (const int*)d_in[1];
  const float* W1 = (const float*)d_in[2];
  const float* b1 = (const float*)d_in[3];
  const float* W2 = (const float*)d_in[4];
  const float* b2 = (const float*)d_in[5];
  const float* gamma = (const float*)d_in[6];
  const float* beta = (const float*)d_in[7];
  float* out = (float*)d_out;

  char* ws = (char*)d_ws;
  unsigned short* x_bf = (unsigned short*)ws;                  // 64 MiB
  unsigned short* h_bf = (unsigned short*)(ws + 67108864);     // 64 MiB
  char* base2 = ws + 134217728;
  float* seg_sums = (float*)(base2);            // 16 KiB (zeroed by k_prep)
  float* colsum   = (float*)(base2 + 16384);    // 1 KiB  (zeroed by k_prep)
  float* colsumsq = (float*)(base2 + 17408);    // 1 KiB  (zeroed by k_prep)
  float* z        = (float*)(base2 + 18432);    // 16 KiB
  unsigned short* w1t = (unsigned short*)(base2 + 36864);      // 128 KiB

  k_prep<<<16, 256, 0, stream>>>(W1, w1t, seg_sums);
  k_segsum_convert<<<1024, 256, 0, stream>>>(x, o, x_bf, seg_sums);
  k_seg_mlp<<<16, 256, 0, stream>>>(o, seg_sums, W1, b1, W2, b2, z);
  k_gemm<<<2048, 256, 0, stream>>>(x_bf, w1t, o, z, h_bf, colsum, colsumsq);
  k_bn_apply<<<32768, 256, 0, stream>>>(h_bf, colsum, colsumsq, gamma, beta, out);
}